// Round 5
// baseline (162.992 us; speedup 1.0000x reference)
//
#include <hip/hip_runtime.h>
#include <float.h>
#include <stdint.h>

#define B_  2
#define S_  2048
#define N_  1024
#define H_  1024
#define NH_ 16
#define K_  1024

typedef __attribute__((ext_vector_type(8))) short bf16x8;
typedef __attribute__((ext_vector_type(4))) float f32x4;

typedef __attribute__((address_space(3))) uint32_t lds_u32;
typedef __attribute__((address_space(1))) uint32_t glb_u32;

// async global->LDS, 16B per lane; LDS dest = wave-uniform base + lane*16
__device__ __forceinline__ void gload16(void* l, const void* g) {
    __builtin_amdgcn_global_load_lds((const glb_u32*)g, (lds_u32*)l, 16, 0, 0);
}

// round-to-nearest-even fp32 -> bf16 bits
__device__ __forceinline__ ushort f2bf(float f) {
    uint32_t u = __float_as_uint(f);
    u = (u + 0x7fffu + ((u >> 16) & 1u)) >> 16;
    return (ushort)u;
}

#if __has_builtin(__builtin_amdgcn_cvt_pk_bf16_f32)
typedef __attribute__((ext_vector_type(2))) __bf16 bfp2;
__device__ __forceinline__ uint pk2(float a, float b) {
    bfp2 v = __builtin_amdgcn_cvt_pk_bf16_f32(a, b);
    return __builtin_bit_cast(uint, v);
}
#else
__device__ __forceinline__ uint pk2(float a, float b) {
    return (uint)f2bf(a) | ((uint)f2bf(b) << 16);
}
#endif

__device__ __forceinline__ float fexp2(float x) {
#if __has_builtin(__builtin_amdgcn_exp2f)
    return __builtin_amdgcn_exp2f(x);
#else
    return exp2f(x);
#endif
}

#define SC2 0.180336880f   /* (1/sqrt(64)) * log2(e) — folded into Q proj */

// ---------------------------------------------------------------------------
// Fused prep: fp32->bf16 converts + prefix counts + Vm zero-init.
// ws layout (ushort): qx 0..4M | kvx 4..6M | wq 6M | wk 7M | wv 8M | wo 9M
// ---------------------------------------------------------------------------
__global__ __launch_bounds__(256) void prep_kernel(const float* __restrict__ tq,
        const float* __restrict__ kv, const float* __restrict__ wq,
        const float* __restrict__ wk, const float* __restrict__ wv,
        const float* __restrict__ wo, const int* __restrict__ ends,
        ushort* __restrict__ dst, int* __restrict__ cnt, float* __restrict__ Vm)
{
    int blk = blockIdx.x;
    if (blk >= 5120) {
        if (blk == 5128) {   // zero Vm (2048 floats)
            float4 z = make_float4(0.f, 0.f, 0.f, 0.f);
            *(float4*)(Vm + threadIdx.x * 8) = z;
            *(float4*)(Vm + threadIdx.x * 8 + 4) = z;
            return;
        }
        int t = (blk - 5120) * 256 + threadIdx.x;
        if (t < S_) {
            int lo = 0, hi = N_;
            while (lo < hi) { int mid = (lo + hi) >> 1; if (ends[mid] <= t) lo = mid + 1; else hi = mid; }
            cnt[t] = lo;
        }
        return;
    }
    const float* src; size_t base;
    if (blk < 2048)      { src = tq; base = 0;       }
    else if (blk < 3072) { src = kv; base = 4194304; blk -= 2048; }
    else if (blk < 3584) { src = wq; base = 6291456; blk -= 3072; }
    else if (blk < 4096) { src = wk; base = 7340032; blk -= 3584; }
    else if (blk < 4608) { src = wv; base = 8388608; blk -= 4096; }
    else                 { src = wo; base = 9437184; blk -= 4608; }
    size_t i = (size_t)blk * 2048 + threadIdx.x * 8;
    float4 a = *(const float4*)(src + i);
    float4 b = *(const float4*)(src + i + 4);
    uint4 o;
    o.x = pk2(a.x, a.y); o.y = pk2(a.z, a.w);
    o.z = pk2(b.x, b.y); o.w = pk2(b.z, b.w);
    *(uint4*)(dst + base + i) = o;
}

// ---------------------------------------------------------------------------
// Unified 128x128-tile bf16 MFMA GEMM (512 thr = 8 waves, BK=64, XOR-swizzled
// LDS via global_load_lds w=16).
// mode 0 (512 WGs): idx<256 -> Qp = qx@Wq^T * SC2; idx<384 -> Kp = kvx@Wk^T;
//   else -> VtG = transpose-per-head(kvx@Wv^T), + per-(b,h,d) V column sums
//   atomically accumulated into Vm (vmean fused).
// mode 1 (256 WGs): out = AO@Wo^T (fp32).
// ---------------------------------------------------------------------------
__global__ __launch_bounds__(512) void gemm_all(int mode,
        const ushort* __restrict__ qx, const ushort* __restrict__ kvx,
        const ushort* __restrict__ wq, const ushort* __restrict__ wk,
        const ushort* __restrict__ wv, const ushort* __restrict__ wo,
        ushort* __restrict__ Qp, ushort* __restrict__ Kp,
        ushort* __restrict__ VtG, const ushort* __restrict__ AO,
        float* __restrict__ outF, float* __restrict__ Vm)
{
    __shared__ __align__(16) ushort smem[17408];
    ushort* Xs = smem;
    ushort* Ws = smem + 8192;

    const ushort* X; const ushort* W; void* Yp; int kind; float scale = 1.f;
    int bm, bn;
    if (mode == 1) {
        X = AO; W = wo; Yp = outF; kind = 1;
        bm = (blockIdx.x >> 3) * 128; bn = (blockIdx.x & 7) * 128;
    } else {
        int idx = blockIdx.x;
        if (idx < 256)      { X = qx;  W = wq; Yp = Qp;  kind = 0; scale = SC2;
                              bm = (idx >> 3) * 128; bn = (idx & 7) * 128; }
        else if (idx < 384) { int j = idx - 256; X = kvx; W = wk; Yp = Kp; kind = 0;
                              bm = (j >> 3) * 128; bn = (j & 7) * 128; }
        else                { int j = idx - 384; X = kvx; W = wv; Yp = VtG; kind = 2;
                              bm = (j >> 3) * 128; bn = (j & 7) * 128; }
    }

    const int tid = threadIdx.x;
    const int lane = tid & 63, w = tid >> 6;
    const int wy = w >> 1, wx = w & 1;
    const int c = lane & 15, g = lane >> 4;

    f32x4 acc[2][4] = {};

    for (int kt = 0; kt < 16; ++kt) {
        const int k0 = kt * 64;
#pragma unroll
        for (int j = 0; j < 2; ++j) {
            int u = w * 128 + j * 64 + lane;
            int row = u >> 3, gs = (u & 7) ^ (row & 7);
            gload16(Xs + (w * 128 + j * 64) * 8, X + (size_t)(bm + row) * K_ + k0 + gs * 8);
            gload16(Ws + (w * 128 + j * 64) * 8, W + (size_t)(bn + row) * K_ + k0 + gs * 8);
        }
        __syncthreads();
#pragma unroll
        for (int ks = 0; ks < 2; ++ks) {
            bf16x8 af[2], bfr[4];
#pragma unroll
            for (int mi = 0; mi < 2; ++mi) {
                int row = wy * 32 + mi * 16 + c;
                int s = ks * 4 + g;
                af[mi] = *(const bf16x8*)(Xs + (row * 8 + (s ^ (row & 7))) * 8);
            }
#pragma unroll
            for (int ni = 0; ni < 4; ++ni) {
                int row = wx * 64 + ni * 16 + c;
                int s = ks * 4 + g;
                bfr[ni] = *(const bf16x8*)(Ws + (row * 8 + (s ^ (row & 7))) * 8);
            }
#pragma unroll
            for (int mi = 0; mi < 2; ++mi)
#pragma unroll
                for (int ni = 0; ni < 4; ++ni)
                    acc[mi][ni] = __builtin_amdgcn_mfma_f32_16x16x32_bf16(af[mi], bfr[ni], acc[mi][ni], 0, 0, 0);
        }
        __syncthreads();
    }

    if (kind == 0) {
        ushort* Y = (ushort*)Yp;
#pragma unroll
        for (int mi = 0; mi < 2; ++mi)
#pragma unroll
            for (int ni = 0; ni < 4; ++ni)
#pragma unroll
                for (int r = 0; r < 4; ++r) {
                    int row = bm + wy * 32 + mi * 16 + g * 4 + r;
                    int col = bn + wx * 64 + ni * 16 + c;
                    Y[(size_t)row * 1024 + col] = f2bf(acc[mi][ni][r] * scale);
                }
    } else if (kind == 1) {
        float* Y = (float*)Yp;
#pragma unroll
        for (int mi = 0; mi < 2; ++mi)
#pragma unroll
            for (int ni = 0; ni < 4; ++ni)
#pragma unroll
                for (int r = 0; r < 4; ++r) {
                    int row = bm + wy * 32 + mi * 16 + g * 4 + r;
                    int col = bn + wx * 64 + ni * 16 + c;
                    Y[(size_t)row * 1024 + col] = acc[mi][ni][r];
                }
    } else {
        ushort* T = smem;                       // [128][136]
#pragma unroll
        for (int mi = 0; mi < 2; ++mi)
#pragma unroll
            for (int ni = 0; ni < 4; ++ni) {
                ushort4 v4;
                v4.x = f2bf(acc[mi][ni][0]); v4.y = f2bf(acc[mi][ni][1]);
                v4.z = f2bf(acc[mi][ni][2]); v4.w = f2bf(acc[mi][ni][3]);
                *(ushort4*)&T[(wx * 64 + ni * 16 + c) * 136 + wy * 32 + mi * 16 + g * 4] = v4;
            }
        __syncthreads();
        ushort* Vt = (ushort*)Yp;
        int b = bm >> 10;
        int rid = tid >> 2, quad = tid & 3;
        int n_c = bn + rid;
        int h = n_c >> 6, d = n_c & 63;
        int m0 = quad * 32;
        ushort* dst = Vt + (size_t)((b * NH_ + h) * 64 + d) * N_ + (bm & (N_ - 1)) + m0;
        float vsum = 0.f;
#pragma unroll
        for (int jj = 0; jj < 4; ++jj) {
            uint4 tt = *(const uint4*)&T[rid * 136 + m0 + jj * 8];
            *(uint4*)(dst + jj * 8) = tt;
            uint uu[4] = {tt.x, tt.y, tt.z, tt.w};
#pragma unroll
            for (int q2 = 0; q2 < 4; ++q2) {
                vsum += __uint_as_float(uu[q2] << 16);
                vsum += __uint_as_float(uu[q2] & 0xffff0000u);
            }
        }
        // reduce over quad (32-col partials) -> one atomic per (row, quad0)
        vsum += __shfl_xor(vsum, 1);
        vsum += __shfl_xor(vsum, 2);
        if (quad == 0) atomicAdd(&Vm[b * 1024 + n_c], vsum);
    }
}

// ---------------------------------------------------------------------------
// Flash-MFMA attention, no-max softmax (Q pre-scaled by SC2). WG = 256 thr
// (4 waves) x 128 queries; each wave owns 2 q-tiles of 16 so every K/V
// fragment ds_read feeds 2 MFMAs. Query-block index goes through the folded
// permutation (tb<8 ? tb : 23-tb) so co-resident WG pairs (id, id+256) get
// complementary tile counts (load balance). Prefix visibility => only
// ceil(cnt[last]/64) KV tiles. cnt==0 queries -> Vm/1024 (reference's
// finfo.min uniform softmax).
// ---------------------------------------------------------------------------
__global__ __launch_bounds__(256) void attn_mfma(const ushort* __restrict__ Qp,
                                                 const ushort* __restrict__ Kp,
                                                 const ushort* __restrict__ VtG,
                                                 const int* __restrict__ cnt,
                                                 const float* __restrict__ Vm,
                                                 ushort* __restrict__ AO)
{
    __shared__ __align__(16) ushort Qs[128 * 64];
    __shared__ __align__(16) ushort Ks[64 * 64];
    __shared__ __align__(16) ushort Vs[64 * 64];
    __shared__ __align__(16) ushort Ps[128][72];

    const int id = blockIdx.x;
    const int b = id & 1, h = (id >> 1) & 15;
    const int tb = id >> 5;
    const int t0 = (tb < 8 ? tb : 23 - tb) << 7;   // folded permutation
    const int tid = threadIdx.x, lane = tid & 63, w = tid >> 6;
    const int c = lane & 15, g = lane >> 4;

    // stage Q tile (128 q x 64 d), swizzled: 1024 units, 4 per lane
#pragma unroll
    for (int jj = 0; jj < 4; ++jj) {
        int u = w * 256 + jj * 64 + lane;
        int row = u >> 3, gs = (u & 7) ^ (row & 7);
        gload16(Qs + (w * 256 + jj * 64) * 8,
                Qp + (size_t)(b * S_ + t0 + row) * H_ + h * 64 + gs * 8);
    }
    const int cntv0 = cnt[t0 + w * 32 + c];
    const int cntv1 = cnt[t0 + w * 32 + 16 + c];
    const int cnt_min = cnt[t0];
    const int ntmax = (cnt[t0 + 127] + 63) >> 6;

    // K/V staging addresses (loop-invariant parts)
    const int u0 = (w * 2) * 64 + lane, row0 = u0 >> 3, gs0 = (u0 & 7) ^ (row0 & 7);
    const int u1 = (w * 2 + 1) * 64 + lane, row1 = u1 >> 3, gs1 = (u1 & 7) ^ (row1 & 7);
    const ushort* kp0 = Kp + (size_t)(b * N_ + row0) * H_ + h * 64 + gs0 * 8;
    const ushort* kp1 = Kp + (size_t)(b * N_ + row1) * H_ + h * 64 + gs1 * 8;
    const ushort* vp0 = VtG + (size_t)((b * NH_ + h) * 64 + row0) * N_ + gs0 * 8;
    const ushort* vp1 = VtG + (size_t)((b * NH_ + h) * 64 + row1) * N_ + gs1 * 8;

    float l0 = 0.f, l1 = 0.f;
    f32x4 o0[4] = {}, o1[4] = {};

    __syncthreads();
    // Q fragments (loop-invariant): 2 q-tiles per wave
    bf16x8 bq0[2], bq1[2];
#pragma unroll
    for (int ks = 0; ks < 2; ++ks) {
        int s = ks * 4 + g;
        int ra = w * 32 + c;
        bq0[ks] = *(const bf16x8*)(Qs + (ra * 8 + (s ^ (ra & 7))) * 8);
        int rb = w * 32 + 16 + c;
        bq1[ks] = *(const bf16x8*)(Qs + (rb * 8 + (s ^ (rb & 7))) * 8);
    }

    for (int nt = 0; nt < ntmax; ++nt) {
        gload16(Ks + (w * 2) * 512, kp0 + (size_t)nt * 64 * H_);
        gload16(Ks + (w * 2 + 1) * 512, kp1 + (size_t)nt * 64 * H_);
        gload16(Vs + (w * 2) * 512, vp0 + nt * 64);
        gload16(Vs + (w * 2 + 1) * 512, vp1 + nt * 64);
        __syncthreads();

        // S^T = K · Q^T for both q-tiles; each ak fragment feeds 2 MFMAs
        f32x4 st0[4] = {}, st1[4] = {};
#pragma unroll
        for (int ntile = 0; ntile < 4; ++ntile)
#pragma unroll
            for (int ks = 0; ks < 2; ++ks) {
                int row = ntile * 16 + c;
                int s = ks * 4 + g;
                bf16x8 ak = *(const bf16x8*)(Ks + (row * 8 + (s ^ (row & 7))) * 8);
                st0[ntile] = __builtin_amdgcn_mfma_f32_16x16x32_bf16(ak, bq0[ks], st0[ntile], 0, 0, 0);
                st1[ntile] = __builtin_amdgcn_mfma_f32_16x16x32_bf16(ak, bq1[ks], st1[ntile], 0, 0, 0);
            }

        // no-max softmax: p = exp2(st) (0 if masked)
        const bool full = ((nt + 1) << 6) <= cnt_min;   // wave-uniform
        float lsum0 = 0.f, lsum1 = 0.f;
        if (full) {
#pragma unroll
            for (int ntile = 0; ntile < 4; ++ntile) {
                float a0 = fexp2(st0[ntile][0]), a1 = fexp2(st0[ntile][1]);
                float a2 = fexp2(st0[ntile][2]), a3 = fexp2(st0[ntile][3]);
                lsum0 += (a0 + a1) + (a2 + a3);
                uint2 pw; pw.x = pk2(a0, a1); pw.y = pk2(a2, a3);
                *(uint2*)&Ps[w * 32 + c][ntile * 16 + g * 4] = pw;
                float b0 = fexp2(st1[ntile][0]), b1 = fexp2(st1[ntile][1]);
                float b2 = fexp2(st1[ntile][2]), b3 = fexp2(st1[ntile][3]);
                lsum1 += (b0 + b1) + (b2 + b3);
                uint2 qw; qw.x = pk2(b0, b1); qw.y = pk2(b2, b3);
                *(uint2*)&Ps[w * 32 + 16 + c][ntile * 16 + g * 4] = qw;
            }
        } else {
            const int base0 = (nt << 6) + g * 4 - cntv0;
            const int base1 = (nt << 6) + g * 4 - cntv1;
#pragma unroll
            for (int ntile = 0; ntile < 4; ++ntile) {
                float a0 = (base0 + ntile * 16 + 0 >= 0) ? 0.f : fexp2(st0[ntile][0]);
                float a1 = (base0 + ntile * 16 + 1 >= 0) ? 0.f : fexp2(st0[ntile][1]);
                float a2 = (base0 + ntile * 16 + 2 >= 0) ? 0.f : fexp2(st0[ntile][2]);
                float a3 = (base0 + ntile * 16 + 3 >= 0) ? 0.f : fexp2(st0[ntile][3]);
                lsum0 += (a0 + a1) + (a2 + a3);
                uint2 pw; pw.x = pk2(a0, a1); pw.y = pk2(a2, a3);
                *(uint2*)&Ps[w * 32 + c][ntile * 16 + g * 4] = pw;
                float b0 = (base1 + ntile * 16 + 0 >= 0) ? 0.f : fexp2(st1[ntile][0]);
                float b1 = (base1 + ntile * 16 + 1 >= 0) ? 0.f : fexp2(st1[ntile][1]);
                float b2 = (base1 + ntile * 16 + 2 >= 0) ? 0.f : fexp2(st1[ntile][2]);
                float b3 = (base1 + ntile * 16 + 3 >= 0) ? 0.f : fexp2(st1[ntile][3]);
                lsum1 += (b0 + b1) + (b2 + b3);
                uint2 qw; qw.x = pk2(b0, b1); qw.y = pk2(b2, b3);
                *(uint2*)&Ps[w * 32 + 16 + c][ntile * 16 + g * 4] = qw;
            }
        }
        lsum0 += __shfl_xor(lsum0, 16); lsum0 += __shfl_xor(lsum0, 32);
        lsum1 += __shfl_xor(lsum1, 16); lsum1 += __shfl_xor(lsum1, 32);
        l0 += lsum0; l1 += lsum1;

        // O += P · V; each bv fragment feeds 2 MFMAs
        bf16x8 ap0[2], ap1[2];
#pragma unroll
        for (int ks = 0; ks < 2; ++ks) {
            ap0[ks] = *(const bf16x8*)&Ps[w * 32 + c][ks * 32 + g * 8];
            ap1[ks] = *(const bf16x8*)&Ps[w * 32 + 16 + c][ks * 32 + g * 8];
        }
#pragma unroll
        for (int dt = 0; dt < 4; ++dt)
#pragma unroll
            for (int ks = 0; ks < 2; ++ks) {
                int row = dt * 16 + c;
                int s = ks * 4 + g;
                bf16x8 bv = *(const bf16x8*)(Vs + (row * 8 + (s ^ (row & 7))) * 8);
                o0[dt] = __builtin_amdgcn_mfma_f32_16x16x32_bf16(ap0[ks], bv, o0[dt], 0, 0, 0);
                o1[dt] = __builtin_amdgcn_mfma_f32_16x16x32_bf16(ap1[ks], bv, o1[dt], 0, 0, 0);
            }
        __syncthreads();
    }

    // epilogue (both q-tiles)
#pragma unroll
    for (int qt = 0; qt < 2; ++qt) {
        float invl = 1.f / (qt == 0 ? l0 : l1);
        f32x4* o = (qt == 0 ? o0 : o1);
        float lr[4]; int cq[4];
#pragma unroll
        for (int r = 0; r < 4; ++r) {
            lr[r] = __shfl(invl, g * 4 + r);
            cq[r] = cnt[t0 + w * 32 + qt * 16 + g * 4 + r];
        }
#pragma unroll
        for (int dt = 0; dt < 4; ++dt)
#pragma unroll
            for (int r = 0; r < 4; ++r) {
                int q = t0 + w * 32 + qt * 16 + g * 4 + r;
                float val = o[dt][r] * lr[r];
                if (cq[r] == 0) val = Vm[b * 1024 + h * 64 + dt * 16 + c] * (1.f / 1024.f);
                AO[(size_t)(b * S_ + q) * H_ + h * 64 + dt * 16 + c] = f2bf(val);
            }
    }
}

// ---------------------------------------------------------------------------
extern "C" void kernel_launch(void* const* d_in, const int* in_sizes, int n_in,
                              void* d_out, int out_size, void* d_ws, size_t ws_size,
                              hipStream_t stream) {
    const float* token_q    = (const float*)d_in[0];
    const float* block_kv   = (const float*)d_in[1];
    const int*   block_ends = (const int*)d_in[2];
    const float* Wq = (const float*)d_in[3];
    const float* Wk = (const float*)d_in[4];
    const float* Wv = (const float*)d_in[5];
    const float* Wo = (const float*)d_in[6];
    float* out = (float*)d_out;

    // ws layout (ushort units):
    // qx 0..4M | kvx 4..6M | wq 6M | wk 7M | wv 8M | wo 9M | Qp 10..14M (AO
    // aliases Qp: per-WG read-before-write) | Kp 14..16M | VtG 16..18M | cnt | Vm
    ushort* ws  = (ushort*)d_ws;
    ushort* qx  = ws;
    ushort* kvx = ws + (size_t)4 * 1024 * 1024;
    ushort* wqb = ws + (size_t)6 * 1024 * 1024;
    ushort* wkb = ws + (size_t)7 * 1024 * 1024;
    ushort* wvb = ws + (size_t)8 * 1024 * 1024;
    ushort* wob = ws + (size_t)9 * 1024 * 1024;
    ushort* Qp  = ws + (size_t)10 * 1024 * 1024;
    ushort* Kp  = ws + (size_t)14 * 1024 * 1024;
    ushort* VtG = ws + (size_t)16 * 1024 * 1024;
    int*    cnt = (int*)(ws + (size_t)18 * 1024 * 1024);
    float*  Vm  = (float*)(ws + (size_t)18 * 1024 * 1024 + 4096);

    // fused converts + counts + Vm zero
    prep_kernel<<<5129, 256, 0, stream>>>(token_q, block_kv, Wq, Wk, Wv, Wo,
                                          block_ends, ws, cnt, Vm);
    // fused Q + K + V projections (V also accumulates Vm)
    gemm_all<<<512, 512, 0, stream>>>(0, qx, kvx, wqb, wkb, wvb, wob,
                                      Qp, Kp, VtG, nullptr, nullptr, Vm);
    // attention -> AO (aliases Qp)
    attn_mfma<<<512, 256, 0, stream>>>(Qp, Kp, VtG, cnt, Vm, Qp);
    // output projection -> fp32 out
    gemm_all<<<256, 512, 0, stream>>>(1, qx, kvx, wqb, wkb, wvb, wob,
                                      Qp, Kp, VtG, Qp, out, Vm);
}